// Round 2
// baseline (2191.414 us; speedup 1.0000x reference)
//
#include <hip/hip_runtime.h>

static constexpr int N_NODES = 100000;
static constexpr int N_EDGES = 3200000;
static constexpr int NC16    = N_NODES * 16;   // 1.6M

// ---------- small float4 helpers ----------
__device__ __forceinline__ float4 v4fma(float s, float4 w, float4 acc) {
    acc.x = fmaf(s, w.x, acc.x);
    acc.y = fmaf(s, w.y, acc.y);
    acc.z = fmaf(s, w.z, acc.z);
    acc.w = fmaf(s, w.w, acc.w);
    return acc;
}

// broadcast all 4 components from quad-lane KK (v_mov_b32 dpp quad_perm — VALU pipe)
template<int KK>
__device__ __forceinline__ float4 qbcast(float4 a) {
    constexpr int ctrl = KK * 0x55;   // quad_perm:[KK,KK,KK,KK]
    float4 r;
    r.x = __int_as_float(__builtin_amdgcn_mov_dpp(__float_as_int(a.x), ctrl, 0xF, 0xF, true));
    r.y = __int_as_float(__builtin_amdgcn_mov_dpp(__float_as_int(a.y), ctrl, 0xF, 0xF, true));
    r.z = __int_as_float(__builtin_amdgcn_mov_dpp(__float_as_int(a.z), ctrl, 0xF, 0xF, true));
    r.w = __int_as_float(__builtin_amdgcn_mov_dpp(__float_as_int(a.w), ctrl, 0xF, 0xF, true));
    return r;
}

// ew(channels of this lane) += sum over k in [4*KK, 4*KK+4) of a[k] * Wcol[k]
template<int KK>
__device__ __forceinline__ float4 ewstep(float4 a, const float4* wc, float4 ew) {
    float4 v = qbcast<KK>(a);
    ew = v4fma(v.x, wc[4*KK + 0], ew);
    ew = v4fma(v.y, wc[4*KK + 1], ew);
    ew = v4fma(v.z, wc[4*KK + 2], ew);
    ew = v4fma(v.w, wc[4*KK + 3], ew);
    return ew;
}

// ---------------- init: deg = 1 (self loop), accumulators = 0 ----------------
__global__ __launch_bounds__(256)
void k_init(float* deg, float* accA, float* accB) {
    int t = blockIdx.x * 256 + threadIdx.x;
    if (t < NC16) { deg[t] = 1.0f; accA[t] = 0.0f; accB[t] = 0.0f; }
}

// ---------------- edge pass (ONE-SHOT: one edge per quad, no loop) ----------------
// 4 lanes per edge; lane owns channels [4*c4, 4*c4+4).
// HAS_P=false: acc[dst] += ew            (degree pass)
// HAS_P=true : acc[dst] += ew * p[src]   (conv message pass)
// No thread ever waits on an atomic: loads -> gather -> atomics -> retire.
template<bool HAS_P>
__global__ __launch_bounds__(256)
void k_edge(const float* __restrict__ ea, const int* __restrict__ srcI,
            const int* __restrict__ dstI, const float* __restrict__ We,
            const float* __restrict__ be, const float* __restrict__ p,
            float* __restrict__ acc)
{
    const int tid = blockIdx.x * 256 + threadIdx.x;
    const int e   = tid >> 2;
    if (e >= N_EDGES) return;
    const int c4  = threadIdx.x & 3;

    // start the dependent chain first: indices, then the edge-attr vector
    const int d = dstI[e];
    const int s = HAS_P ? srcI[e] : 0;
    const float4* ea4 = (const float4*)ea;
    float4 a = ea4[e * 4 + c4];               // coalesced: lane-contiguous

    // kick off the p-gather as soon as s arrives (independent of ew math)
    float4 pv;
    if (HAS_P) {
        const float4* p4 = (const float4*)p;
        pv = p4[s * 4 + c4];                  // 16B gather, quad-contiguous 64B/edge
    }

    // We columns: 1 KB/wave, L1-resident after first wave on the CU
    float4 wc[16];
    const float4* We4 = (const float4*)We;
#pragma unroll
    for (int k = 0; k < 16; ++k) wc[k] = We4[k * 4 + c4];
    const float4 bev = ((const float4*)be)[c4];

    float4 ew = bev;
    ew = ewstep<0>(a, wc, ew);
    ew = ewstep<1>(a, wc, ew);
    ew = ewstep<2>(a, wc, ew);
    ew = ewstep<3>(a, wc, ew);

    float4 val;
    if (HAS_P) {
        val.x = ew.x * pv.x; val.y = ew.y * pv.y;
        val.z = ew.z * pv.z; val.w = ew.w * pv.w;
    } else {
        val = ew;
    }

    float* o = acc + d * 16 + c4 * 4;
    unsafeAtomicAdd(o + 0, val.x);            // HW global_atomic_add_f32
    unsafeAtomicAdd(o + 1, val.y);
    unsafeAtomicAdd(o + 2, val.z);
    unsafeAtomicAdd(o + 3, val.w);
}

// ---------------- deg -> dinv (in place) ----------------
__global__ __launch_bounds__(256)
void k_dinv(float* dd) {
    int t = blockIdx.x * 256 + threadIdx.x;
    if (t < NC16) {
        float d = dd[t];
        dd[t] = (d > 0.0f) ? rsqrtf(d + 1e-12f) : 0.0f;   // d>0 so abs(d)==d
    }
}

// ---------------- p = dinv * (x @ W1) ----------------
// block = 256 threads; thread = (node_lane nl 0..63, c4 0..3); 4 nodes per thread.
__global__ __launch_bounds__(256)
void k_xw1(const float* __restrict__ x, const float* __restrict__ W1,
           const float* __restrict__ dinv, float* __restrict__ p)
{
    __shared__ float4 w1s[512];               // [k][c4], k=0..127
    const int t = threadIdx.x;
    const float4* W14 = (const float4*)W1;
    w1s[t]       = W14[t];
    w1s[t + 256] = W14[t + 256];
    __syncthreads();

    const int c4 = t & 3;
    const int nl = t >> 2;                    // 0..63
    const int nb = blockIdx.x * 256;
    int node[4];
    float4 acc[4];
#pragma unroll
    for (int i = 0; i < 4; ++i) {
        node[i] = nb + i * 64 + nl;
        acc[i]  = make_float4(0.f, 0.f, 0.f, 0.f);
    }
    const float4* x4 = (const float4*)x;

    for (int k4 = 0; k4 < 32; ++k4) {
        float4 wv0 = w1s[(k4 * 4 + 0) * 4 + c4];
        float4 wv1 = w1s[(k4 * 4 + 1) * 4 + c4];
        float4 wv2 = w1s[(k4 * 4 + 2) * 4 + c4];
        float4 wv3 = w1s[(k4 * 4 + 3) * 4 + c4];
#pragma unroll
        for (int i = 0; i < 4; ++i) {
            int nn = node[i] < N_NODES ? node[i] : (N_NODES - 1);
            float4 xv = x4[nn * 32 + k4];
            acc[i] = v4fma(xv.x, wv0, acc[i]);
            acc[i] = v4fma(xv.y, wv1, acc[i]);
            acc[i] = v4fma(xv.z, wv2, acc[i]);
            acc[i] = v4fma(xv.w, wv3, acc[i]);
        }
    }
    const float4* dinv4 = (const float4*)dinv;
    float4* pp = (float4*)p;
#pragma unroll
    for (int i = 0; i < 4; ++i) {
        if (node[i] < N_NODES) {
            float4 dv = dinv4[node[i] * 4 + c4];
            float4 o;
            o.x = dv.x * acc[i].x; o.y = dv.y * acc[i].y;
            o.z = dv.z * acc[i].z; o.w = dv.w * acc[i].w;
            pp[node[i] * 4 + c4] = o;
        }
    }
}

// ---------------- conv1 epilogue + h1@W2 + make p2 (in place over p) ----------------
// h1 = relu(dinv*(acc1 + p1) + b1); h2 = h1 @ W2 (quad dpp); p2 = dinv * h2
__global__ __launch_bounds__(256)
void k_mid(const float* __restrict__ accA, const float* __restrict__ dinv,
           const float* __restrict__ W2, const float* __restrict__ b1,
           float* __restrict__ p)
{
    const int tid = blockIdx.x * 256 + threadIdx.x;
    const int q   = tid >> 2;                 // node
    if (q >= N_NODES) return;                 // whole quads exit together
    const int c4 = threadIdx.x & 3;

    float4 wc[16];
    const float4* W24 = (const float4*)W2;
#pragma unroll
    for (int k = 0; k < 16; ++k) wc[k] = W24[k * 4 + c4];
    const float4 b1v = ((const float4*)b1)[c4];

    const float4 av = ((const float4*)accA)[q * 4 + c4];
    const float4 pv = ((const float4*)p)[q * 4 + c4];
    const float4 dv = ((const float4*)dinv)[q * 4 + c4];

    float4 h1;
    h1.x = fmaxf(fmaf(dv.x, av.x + pv.x, b1v.x), 0.f);
    h1.y = fmaxf(fmaf(dv.y, av.y + pv.y, b1v.y), 0.f);
    h1.z = fmaxf(fmaf(dv.z, av.z + pv.z, b1v.z), 0.f);
    h1.w = fmaxf(fmaf(dv.w, av.w + pv.w, b1v.w), 0.f);

    float4 h2 = make_float4(0.f, 0.f, 0.f, 0.f);
    h2 = ewstep<0>(h1, wc, h2);
    h2 = ewstep<1>(h1, wc, h2);
    h2 = ewstep<2>(h1, wc, h2);
    h2 = ewstep<3>(h1, wc, h2);

    float4 o;
    o.x = dv.x * h2.x; o.y = dv.y * h2.y;
    o.z = dv.z * h2.z; o.w = dv.w * h2.w;
    ((float4*)p)[q * 4 + c4] = o;
}

// ---------------- final epilogue: out = dinv*(acc2 + p2) + b2 ----------------
__global__ __launch_bounds__(256)
void k_out(const float* __restrict__ accB, const float* __restrict__ dinv,
           const float* __restrict__ p, const float* __restrict__ b2,
           float* __restrict__ out)
{
    const int tid = blockIdx.x * 256 + threadIdx.x;
    const int q   = tid >> 2;
    if (q >= N_NODES) return;
    const int c4 = threadIdx.x & 3;
    const float4 b2v = ((const float4*)b2)[c4];
    const float4 av = ((const float4*)accB)[q * 4 + c4];
    const float4 pv = ((const float4*)p)[q * 4 + c4];
    const float4 dv = ((const float4*)dinv)[q * 4 + c4];
    float4 o;
    o.x = fmaf(dv.x, av.x + pv.x, b2v.x);
    o.y = fmaf(dv.y, av.y + pv.y, b2v.y);
    o.z = fmaf(dv.z, av.z + pv.z, b2v.z);
    o.w = fmaf(dv.w, av.w + pv.w, b2v.w);
    ((float4*)out)[q * 4 + c4] = o;
}

extern "C" void kernel_launch(void* const* d_in, const int* in_sizes, int n_in,
                              void* d_out, int out_size, void* d_ws, size_t ws_size,
                              hipStream_t stream)
{
    const float* x   = (const float*)d_in[0];
    const int*   ei  = (const int*)d_in[1];
    const float* ea  = (const float*)d_in[2];
    const float* We  = (const float*)d_in[3];
    const float* be  = (const float*)d_in[4];
    const float* W1  = (const float*)d_in[5];
    const float* b1  = (const float*)d_in[6];
    const float* W2  = (const float*)d_in[7];
    const float* b2  = (const float*)d_in[8];
    float* out = (float*)d_out;

    const int* srcI = ei;            // edge_index[0]
    const int* dstI = ei + N_EDGES;  // edge_index[1]

    // workspace carve: 4 arrays of N*16 fp32 = 25.6 MB
    float* dinv = (float*)d_ws;      // deg, then dinv in place
    float* p    = dinv + NC16;       // p1, then p2 in place
    float* accA = p + NC16;
    float* accB = accA + NC16;

    const dim3 blk(256);
    const dim3 egrid((N_EDGES * 4) / 256);    // 50,000 blocks, one edge per quad
    hipLaunchKernelGGL(k_init, dim3(NC16 / 256), blk, 0, stream, dinv, accA, accB);
    hipLaunchKernelGGL((k_edge<false>), egrid, blk, 0, stream,
                       ea, srcI, dstI, We, be, (const float*)nullptr, dinv);
    hipLaunchKernelGGL(k_dinv, dim3(NC16 / 256), blk, 0, stream, dinv);
    hipLaunchKernelGGL(k_xw1, dim3((N_NODES + 255) / 256), blk, 0, stream, x, W1, dinv, p);
    hipLaunchKernelGGL((k_edge<true>), egrid, blk, 0, stream,
                       ea, srcI, dstI, We, be, p, accA);
    hipLaunchKernelGGL(k_mid, dim3((N_NODES * 4 + 255) / 256), blk, 0, stream,
                       accA, dinv, W2, b1, p);
    hipLaunchKernelGGL((k_edge<true>), egrid, blk, 0, stream,
                       ea, srcI, dstI, We, be, p, accB);
    hipLaunchKernelGGL(k_out, dim3((N_NODES * 4 + 255) / 256), blk, 0, stream,
                       accB, dinv, p, b2, out);
}

// Round 4
// 680.160 us; speedup vs baseline: 3.2219x; 3.2219x over previous
//
#include <hip/hip_runtime.h>

static constexpr int N_NODES = 100000;
static constexpr int N_EDGES = 3200000;
static constexpr int NC16    = N_NODES * 16;         // 1.6M
static constexpr int RB      = 256;                  // nodes per bucket
static constexpr int NB      = (N_NODES + RB - 1) / RB;   // 391 buckets
static constexpr int CAP     = 9000;                 // per-bucket capacity (mean 8192, +9 sigma)
static constexpr int EPB     = 8192;                 // edges per partition block
static constexpr int NPB     = (N_EDGES + EPB - 1) / EPB; // 391 partition blocks

// ---------- small float4 helpers ----------
__device__ __forceinline__ float4 v4fma(float s, float4 w, float4 acc) {
    acc.x = fmaf(s, w.x, acc.x);
    acc.y = fmaf(s, w.y, acc.y);
    acc.z = fmaf(s, w.z, acc.z);
    acc.w = fmaf(s, w.w, acc.w);
    return acc;
}

// broadcast all 4 components from quad-lane KK (v_mov_b32 dpp quad_perm — VALU pipe)
template<int KK>
__device__ __forceinline__ float4 qbcast(float4 a) {
    constexpr int ctrl = KK * 0x55;   // quad_perm:[KK,KK,KK,KK]
    float4 r;
    r.x = __int_as_float(__builtin_amdgcn_mov_dpp(__float_as_int(a.x), ctrl, 0xF, 0xF, true));
    r.y = __int_as_float(__builtin_amdgcn_mov_dpp(__float_as_int(a.y), ctrl, 0xF, 0xF, true));
    r.z = __int_as_float(__builtin_amdgcn_mov_dpp(__float_as_int(a.z), ctrl, 0xF, 0xF, true));
    r.w = __int_as_float(__builtin_amdgcn_mov_dpp(__float_as_int(a.w), ctrl, 0xF, 0xF, true));
    return r;
}

// ew(channels of this lane) += sum over k in [4*KK, 4*KK+4) of a[k] * Wcol[k]
template<int KK>
__device__ __forceinline__ float4 ewstep(float4 a, const float4* wc, float4 ew) {
    float4 v = qbcast<KK>(a);
    ew = v4fma(v.x, wc[4*KK + 0], ew);
    ew = v4fma(v.y, wc[4*KK + 1], ew);
    ew = v4fma(v.z, wc[4*KK + 2], ew);
    ew = v4fma(v.w, wc[4*KK + 3], ew);
    return ew;
}

// ---------------- zero gcount (kernel, NOT hipMemsetAsync — graph-capture-proof) ----
__global__ __launch_bounds__(256)
void k_zero(int* g) {
    int t = blockIdx.x * 256 + threadIdx.x;
    if (t < NB) g[t] = 0;
}

// ================= bucket-partition path (no device fp32 atomics) =================

// Partition: group edges by dst bucket (dst>>8). Per-block LDS histogram ->
// ONE global int atomic per (block,bucket) to reserve a contiguous chunk ->
// scatter 8B meta records {eid, src<<8|dst&255}.
__global__ __launch_bounds__(256)
void k_part(const int* __restrict__ srcI, const int* __restrict__ dstI,
            int* __restrict__ gcount, int2* __restrict__ meta)
{
    __shared__ int hist[NB];
    const int tid  = threadIdx.x;
    const int e0   = blockIdx.x * EPB;
    const int ecnt = min(EPB, N_EDGES - e0);
    for (int t = tid; t < NB; t += 256) hist[t] = 0;
    __syncthreads();
    for (int i = tid; i < ecnt; i += 256) {
        int d = dstI[e0 + i];
        atomicAdd(&hist[d >> 8], 1);              // LDS int atomic (exact, commutative)
    }
    __syncthreads();
    for (int t = tid; t < NB; t += 256) {
        int h = hist[t];
        hist[t] = (h > 0) ? atomicAdd(&gcount[t], h) : 0;   // one global atomic per bucket
    }
    __syncthreads();
    for (int i = tid; i < ecnt; i += 256) {
        int e = e0 + i;
        int d = dstI[e];
        int s = srcI[e];
        int b = d >> 8;
        int pos = atomicAdd(&hist[b], 1);         // LDS cursor
        if (pos < CAP)                            // OOB insurance (never expected)
            meta[b * CAP + pos] = make_int2(e, (s << 8) | (d & 255));
    }
}

// Bucket accumulation: block <-> bucket; fp64 LDS accumulator (ds_add_f64 —
// order noise ~1e-15, run-to-run deterministic in practice), plain coalesced
// stores at the end. 4 lanes per edge, lane owns 4 channels.
// HAS_P=false: acc[dst] += ew ; HAS_P=true: acc[dst] += ew * p[src]
template<bool HAS_P>
__global__ __launch_bounds__(512)
void k_bucket(const float* __restrict__ ea, const int2* __restrict__ meta,
              const int* __restrict__ gcount, const float* __restrict__ We,
              const float* __restrict__ be, const float* __restrict__ p,
              float* __restrict__ acc)
{
    __shared__ double accS[RB * 16];              // 32 KB
    const int tid = threadIdx.x;
    const int b   = blockIdx.x;
    for (int t = tid; t < RB * 16; t += 512) accS[t] = 0.0;

    const int c4 = tid & 3;
    float4 wc[16];
    const float4* We4 = (const float4*)We;
#pragma unroll
    for (int k = 0; k < 16; ++k) wc[k] = We4[k * 4 + c4];
    const float4 bev = ((const float4*)be)[c4];
    const int cnt = min(gcount[b], CAP);
    const int2* ml = meta + b * CAP;
    const float4* ea4 = (const float4*)ea;
    const float4* p4  = (const float4*)p;
    __syncthreads();

#pragma unroll 2
    for (int i = tid >> 2; i < cnt; i += 128) {
        int2 m = ml[i];                           // 16 lanes share -> 128B/wave coalesced
        float4 a = ea4[m.x * 4 + c4];             // exactly one 64B line per edge
        float4 pv;
        if (HAS_P) pv = p4[((unsigned)m.y >> 8) * 4 + c4];   // p is 6.4MB, L2/LLC-hot
        const int dl = m.y & 255;
        float4 ew = bev;
        ew = ewstep<0>(a, wc, ew);
        ew = ewstep<1>(a, wc, ew);
        ew = ewstep<2>(a, wc, ew);
        ew = ewstep<3>(a, wc, ew);
        double* o = accS + dl * 16 + c4 * 4;
        if (HAS_P) {
            atomicAdd(o + 0, (double)(ew.x * pv.x));   // ds_add_f64, on-CU
            atomicAdd(o + 1, (double)(ew.y * pv.y));
            atomicAdd(o + 2, (double)(ew.z * pv.z));
            atomicAdd(o + 3, (double)(ew.w * pv.w));
        } else {
            atomicAdd(o + 0, (double)ew.x);
            atomicAdd(o + 1, (double)ew.y);
            atomicAdd(o + 2, (double)ew.z);
            atomicAdd(o + 3, (double)ew.w);
        }
    }
    __syncthreads();

    // store: thread t handles 4 channels of node (t>>2) -> coalesced float4
    for (int t = tid; t < RB * 4; t += 512) {     // 1024 float4s
        int nl = t >> 2;
        int ng = b * RB + nl;
        if (ng < N_NODES) {
            const double* s = accS + nl * 16 + (t & 3) * 4;
            float4 o;
            o.x = (float)s[0]; o.y = (float)s[1];
            o.z = (float)s[2]; o.w = (float)s[3];
            ((float4*)acc)[ng * 4 + (t & 3)] = o;
        }
    }
}

// ---------------- deg -> dinv (in place; adds the +1 self loop) ----------------
__global__ __launch_bounds__(256)
void k_dinv(float* dd) {
    int t = blockIdx.x * 256 + threadIdx.x;
    if (t < NC16) {
        float d = dd[t] + 1.0f;
        dd[t] = (d > 0.0f) ? rsqrtf(d + 1e-12f) : 0.0f;   // d>0 so abs(d)==d
    }
}

// ---------------- p = dinv * (x @ W1) ----------------
__global__ __launch_bounds__(256)
void k_xw1(const float* __restrict__ x, const float* __restrict__ W1,
           const float* __restrict__ dinv, float* __restrict__ p)
{
    __shared__ float4 w1s[512];               // [k][c4], k=0..127
    const int t = threadIdx.x;
    const float4* W14 = (const float4*)W1;
    w1s[t]       = W14[t];
    w1s[t + 256] = W14[t + 256];
    __syncthreads();

    const int c4 = t & 3;
    const int nl = t >> 2;                    // 0..63
    const int nb = blockIdx.x * 256;
    int node[4];
    float4 acc[4];
#pragma unroll
    for (int i = 0; i < 4; ++i) {
        node[i] = nb + i * 64 + nl;
        acc[i]  = make_float4(0.f, 0.f, 0.f, 0.f);
    }
    const float4* x4 = (const float4*)x;

    for (int k4 = 0; k4 < 32; ++k4) {
        float4 wv0 = w1s[(k4 * 4 + 0) * 4 + c4];
        float4 wv1 = w1s[(k4 * 4 + 1) * 4 + c4];
        float4 wv2 = w1s[(k4 * 4 + 2) * 4 + c4];
        float4 wv3 = w1s[(k4 * 4 + 3) * 4 + c4];
#pragma unroll
        for (int i = 0; i < 4; ++i) {
            int nn = node[i] < N_NODES ? node[i] : (N_NODES - 1);
            float4 xv = x4[nn * 32 + k4];
            acc[i] = v4fma(xv.x, wv0, acc[i]);
            acc[i] = v4fma(xv.y, wv1, acc[i]);
            acc[i] = v4fma(xv.z, wv2, acc[i]);
            acc[i] = v4fma(xv.w, wv3, acc[i]);
        }
    }
    const float4* dinv4 = (const float4*)dinv;
    float4* pp = (float4*)p;
#pragma unroll
    for (int i = 0; i < 4; ++i) {
        if (node[i] < N_NODES) {
            float4 dv = dinv4[node[i] * 4 + c4];
            float4 o;
            o.x = dv.x * acc[i].x; o.y = dv.y * acc[i].y;
            o.z = dv.z * acc[i].z; o.w = dv.w * acc[i].w;
            pp[node[i] * 4 + c4] = o;
        }
    }
}

// ---------------- conv1 epilogue + h1@W2 + make p2 (in place over p) ----------------
__global__ __launch_bounds__(256)
void k_mid(const float* __restrict__ accA, const float* __restrict__ dinv,
           const float* __restrict__ W2, const float* __restrict__ b1,
           float* __restrict__ p)
{
    const int tid = blockIdx.x * 256 + threadIdx.x;
    const int q   = tid >> 2;                 // node
    if (q >= N_NODES) return;
    const int c4 = threadIdx.x & 3;

    float4 wc[16];
    const float4* W24 = (const float4*)W2;
#pragma unroll
    for (int k = 0; k < 16; ++k) wc[k] = W24[k * 4 + c4];
    const float4 b1v = ((const float4*)b1)[c4];

    const float4 av = ((const float4*)accA)[q * 4 + c4];
    const float4 pv = ((const float4*)p)[q * 4 + c4];
    const float4 dv = ((const float4*)dinv)[q * 4 + c4];

    float4 h1;
    h1.x = fmaxf(fmaf(dv.x, av.x + pv.x, b1v.x), 0.f);
    h1.y = fmaxf(fmaf(dv.y, av.y + pv.y, b1v.y), 0.f);
    h1.z = fmaxf(fmaf(dv.z, av.z + pv.z, b1v.z), 0.f);
    h1.w = fmaxf(fmaf(dv.w, av.w + pv.w, b1v.w), 0.f);

    float4 h2 = make_float4(0.f, 0.f, 0.f, 0.f);
    h2 = ewstep<0>(h1, wc, h2);
    h2 = ewstep<1>(h1, wc, h2);
    h2 = ewstep<2>(h1, wc, h2);
    h2 = ewstep<3>(h1, wc, h2);

    float4 o;
    o.x = dv.x * h2.x; o.y = dv.y * h2.y;
    o.z = dv.z * h2.z; o.w = dv.w * h2.w;
    ((float4*)p)[q * 4 + c4] = o;
}

// ---------------- final epilogue: out = dinv*(acc2 + p2) + b2 ----------------
__global__ __launch_bounds__(256)
void k_out(const float* __restrict__ accB, const float* __restrict__ dinv,
           const float* __restrict__ p, const float* __restrict__ b2,
           float* __restrict__ out)
{
    const int tid = blockIdx.x * 256 + threadIdx.x;
    const int q   = tid >> 2;
    if (q >= N_NODES) return;
    const int c4 = threadIdx.x & 3;
    const float4 b2v = ((const float4*)b2)[c4];
    const float4 av = ((const float4*)accB)[q * 4 + c4];
    const float4 pv = ((const float4*)p)[q * 4 + c4];
    const float4 dv = ((const float4*)dinv)[q * 4 + c4];
    float4 o;
    o.x = fmaf(dv.x, av.x + pv.x, b2v.x);
    o.y = fmaf(dv.y, av.y + pv.y, b2v.y);
    o.z = fmaf(dv.z, av.z + pv.z, b2v.z);
    o.w = fmaf(dv.w, av.w + pv.w, b2v.w);
    ((float4*)out)[q * 4 + c4] = o;
}

extern "C" void kernel_launch(void* const* d_in, const int* in_sizes, int n_in,
                              void* d_out, int out_size, void* d_ws, size_t ws_size,
                              hipStream_t stream)
{
    const float* x   = (const float*)d_in[0];
    const int*   ei  = (const int*)d_in[1];
    const float* ea  = (const float*)d_in[2];
    const float* We  = (const float*)d_in[3];
    const float* be  = (const float*)d_in[4];
    const float* W1  = (const float*)d_in[5];
    const float* b1  = (const float*)d_in[6];
    const float* W2  = (const float*)d_in[7];
    const float* b2  = (const float*)d_in[8];
    float* out = (float*)d_out;

    const int* srcI = ei;
    const int* dstI = ei + N_EDGES;

    // workspace carve (~54 MB)
    float* dinv = (float*)d_ws;          // deg -> dinv in place       (6.4 MB)
    float* p    = dinv + NC16;           // p1 -> p2 in place          (6.4 MB)
    float* accA = p + NC16;              //                            (6.4 MB)
    float* accB = accA + NC16;           //                            (6.4 MB)
    int2*  meta = (int2*)(accB + NC16);  // NB*CAP*8B                  (28.2 MB)
    int*   gcount = (int*)(meta + (size_t)NB * CAP);  // NB ints

    const dim3 blk(256);
    hipLaunchKernelGGL(k_zero, dim3((NB + 255) / 256), blk, 0, stream, gcount);
    hipLaunchKernelGGL(k_part, dim3(NPB), blk, 0, stream, srcI, dstI, gcount, meta);
    hipLaunchKernelGGL((k_bucket<false>), dim3(NB), dim3(512), 0, stream,
                       ea, meta, gcount, We, be, (const float*)nullptr, dinv);
    hipLaunchKernelGGL(k_dinv, dim3(NC16 / 256), blk, 0, stream, dinv);
    hipLaunchKernelGGL(k_xw1, dim3((N_NODES + 255) / 256), blk, 0, stream, x, W1, dinv, p);
    hipLaunchKernelGGL((k_bucket<true>), dim3(NB), dim3(512), 0, stream,
                       ea, meta, gcount, We, be, p, accA);
    hipLaunchKernelGGL(k_mid, dim3((N_NODES * 4 + 255) / 256), blk, 0, stream,
                       accA, dinv, W2, b1, p);
    hipLaunchKernelGGL((k_bucket<true>), dim3(NB), dim3(512), 0, stream,
                       ea, meta, gcount, We, be, p, accB);
    hipLaunchKernelGGL(k_out, dim3((N_NODES * 4 + 255) / 256), blk, 0, stream,
                       accB, dinv, p, b2, out);
}